// Round 1
// baseline (544.847 us; speedup 1.0000x reference)
//
#include <hip/hip_runtime.h>
#include <stdint.h>

#define B_ 128
#define T_ 1024
#define H_ 512
#define A_ 256
#define G_ 2128

typedef short s16x8 __attribute__((ext_vector_type(8)));
typedef float f32x4 __attribute__((ext_vector_type(4)));

__device__ inline unsigned short f2bf(float f) {
  unsigned u = __float_as_uint(f);
  u += 0x7fff + ((u >> 16) & 1);   // round-to-nearest-even
  return (unsigned short)(u >> 16);
}
__device__ inline float bf2f(unsigned short h) {
  return __uint_as_float(((unsigned)h) << 16);
}
__device__ inline float fast_tanh(float x) {
  x = fminf(15.f, fmaxf(-15.f, x));
  float e = __expf(2.f * x);
  return (e - 1.f) * __builtin_amdgcn_rcpf(e + 1.f);
}

// Build K^T in bf16 hi/lo split, tile-major layout [kb][a][k_in_tile] so pass1
// staging is a contiguous copy. kb = k/32, 16 tiles, each 256x32.
__global__ void prep_kt(const float* __restrict__ K,
                        unsigned short* __restrict__ khi,
                        unsigned short* __restrict__ klo) {
  int flat = blockIdx.x * 256 + threadIdx.x;   // 0..131071
  int kb  = flat >> 13;
  int rem = flat & 8191;
  int a = rem >> 5;
  int k = rem & 31;
  float f = K[(kb * 32 + k) * A_ + a];
  unsigned short hi = f2bf(f);
  float lo = f - bf2f(hi);
  khi[flat] = hi;
  klo[flat] = f2bf(lo);
}

// gp[b][a] = w0 * sum_g genes[b,g]*Wg[g,a] + b_genes[a] + dense_bias[a]  (fp32)
__global__ void gene_proj_k(const float* __restrict__ genes,
                            const float* __restrict__ w0p,
                            const float* __restrict__ Wg,
                            const float* __restrict__ bg,
                            const float* __restrict__ db,
                            float* __restrict__ gp) {
  int b = blockIdx.x;
  int gc = blockIdx.y;      // 0..3, chunks of 532 (4*532 = 2128)
  int a = threadIdx.x;
  int g0 = gc * 532;
  float s = 0.f;
  #pragma unroll 4
  for (int g = g0; g < g0 + 532; ++g)
    s += genes[b * G_ + g] * Wg[g * A_ + a];
  float val = w0p[0] * s;
  if (gc == 0) val += bg[a] + db[a];
  atomicAdd(&gp[b * A_ + a], val);
}

// Pass 1: per block: b, 64 t's, all 256 a's. xv[b,t] = sum_a v_a*tanh(gp[b,a]+proj)
__global__ __launch_bounds__(256) void pass1(
    const float* __restrict__ smiles, const unsigned short* __restrict__ khi,
    const unsigned short* __restrict__ klo, const float* __restrict__ gp,
    const float* __restrict__ v, float* __restrict__ xv) {
  __shared__ unsigned short sA[64 * 32];     // smiles tile bf16, 4 KB
  __shared__ unsigned short sBh[256 * 32];   // K^T hi tile, 16 KB
  __shared__ unsigned short sBl[256 * 32];   // K^T lo tile, 16 KB
  __shared__ float sXV[256];                 // per-wave xv partials

  const int tid = threadIdx.x;
  const int b = blockIdx.y;
  const int t0 = blockIdx.x * 64;
  const int lane = tid & 63;
  const int w = tid >> 6;        // wave id: a-range [w*64, w*64+64)
  const int n = lane & 15;
  const int quad = lane >> 4;

  const float* sb = smiles + ((size_t)b * T_ + t0) * H_;

  f32x4 acc[4][4];
  #pragma unroll
  for (int i = 0; i < 4; ++i)
    #pragma unroll
    for (int j = 0; j < 4; ++j)
      acc[i][j] = (f32x4){0.f, 0.f, 0.f, 0.f};

  const int srow = tid >> 2;     // 0..63
  const int shalf = tid & 3;     // 0..3

  for (int kb = 0; kb < 16; ++kb) {
    const int k0 = kb * 32;
    __syncthreads();
    // stage smiles tile 64x32 fp32 -> bf16
    {
      const float* src = sb + srow * H_ + k0 + shalf * 8;
      float4 f0 = *reinterpret_cast<const float4*>(src);
      float4 f1 = *reinterpret_cast<const float4*>(src + 4);
      ushort4 p0, p1;
      p0.x = f2bf(f0.x); p0.y = f2bf(f0.y); p0.z = f2bf(f0.z); p0.w = f2bf(f0.w);
      p1.x = f2bf(f1.x); p1.y = f2bf(f1.y); p1.z = f2bf(f1.z); p1.w = f2bf(f1.w);
      ushort4* dst = reinterpret_cast<ushort4*>(&sA[srow * 32 + shalf * 8]);
      dst[0] = p0; dst[1] = p1;
    }
    // stage K^T hi/lo tiles (contiguous copy: 64 B per thread each)
    {
      const uint4* hsrc = reinterpret_cast<const uint4*>(khi + kb * 8192 + tid * 32);
      const uint4* lsrc = reinterpret_cast<const uint4*>(klo + kb * 8192 + tid * 32);
      uint4* hdst = reinterpret_cast<uint4*>(&sBh[tid * 32]);
      uint4* ldst = reinterpret_cast<uint4*>(&sBl[tid * 32]);
      #pragma unroll
      for (int i = 0; i < 4; ++i) hdst[i] = hsrc[i];
      #pragma unroll
      for (int i = 0; i < 4; ++i) ldst[i] = lsrc[i];
    }
    __syncthreads();

    s16x8 af[4], bh[4], bl[4];
    #pragma unroll
    for (int i = 0; i < 4; ++i)
      af[i] = *reinterpret_cast<const s16x8*>(&sA[(i * 16 + n) * 32 + quad * 8]);
    #pragma unroll
    for (int j = 0; j < 4; ++j) {
      int ar = w * 64 + j * 16 + n;
      bh[j] = *reinterpret_cast<const s16x8*>(&sBh[ar * 32 + quad * 8]);
      bl[j] = *reinterpret_cast<const s16x8*>(&sBl[ar * 32 + quad * 8]);
    }
    #pragma unroll
    for (int i = 0; i < 4; ++i)
      #pragma unroll
      for (int j = 0; j < 4; ++j) {
        acc[i][j] = __builtin_amdgcn_mfma_f32_16x16x32_bf16(af[i], bh[j], acc[i][j], 0, 0, 0);
        acc[i][j] = __builtin_amdgcn_mfma_f32_16x16x32_bf16(af[i], bl[j], acc[i][j], 0, 0, 0);
      }
  }

  // epilogue: tanh(gp + proj) * v, reduce over a
  float vv[4], gg[4];
  #pragma unroll
  for (int j = 0; j < 4; ++j) {
    int a = w * 64 + j * 16 + n;
    vv[j] = v[a];
    gg[j] = gp[b * A_ + a];
  }
  #pragma unroll
  for (int i = 0; i < 4; ++i) {
    #pragma unroll
    for (int r = 0; r < 4; ++r) {
      float s = 0.f;
      #pragma unroll
      for (int j = 0; j < 4; ++j) {
        float x = acc[i][j][r] + gg[j];
        s += vv[j] * fast_tanh(x);
      }
      s += __shfl_xor(s, 1); s += __shfl_xor(s, 2);
      s += __shfl_xor(s, 4); s += __shfl_xor(s, 8);
      if (n == 0) sXV[w * 64 + i * 16 + quad * 4 + r] = s;
    }
  }
  __syncthreads();
  if (tid < 64)
    xv[(size_t)b * T_ + t0 + tid] =
        sXV[tid] + sXV[64 + tid] + sXV[128 + tid] + sXV[192 + tid];
}

__global__ __launch_bounds__(256) void softmax_k(const float* __restrict__ xv,
                                                 float* __restrict__ alphas) {
  __shared__ float red[8];
  int b = blockIdx.x, tid = threadIdx.x;
  float4 x = *reinterpret_cast<const float4*>(xv + b * T_ + tid * 4);
  float m = fmaxf(fmaxf(x.x, x.y), fmaxf(x.z, x.w));
  #pragma unroll
  for (int o = 1; o < 64; o <<= 1) m = fmaxf(m, __shfl_xor(m, o));
  if ((tid & 63) == 0) red[tid >> 6] = m;
  __syncthreads();
  m = fmaxf(fmaxf(red[0], red[1]), fmaxf(red[2], red[3]));
  float e0 = __expf(x.x - m), e1 = __expf(x.y - m);
  float e2 = __expf(x.z - m), e3 = __expf(x.w - m);
  float s = e0 + e1 + e2 + e3;
  #pragma unroll
  for (int o = 1; o < 64; o <<= 1) s += __shfl_xor(s, o);
  if ((tid & 63) == 0) red[4 + (tid >> 6)] = s;
  __syncthreads();
  s = red[4] + red[5] + red[6] + red[7];
  float inv = 1.f / s;
  float4 o4;
  o4.x = e0 * inv; o4.y = e1 * inv; o4.z = e2 * inv; o4.w = e3 * inv;
  *reinterpret_cast<float4*>(alphas + b * T_ + tid * 4) = o4;
}

// out[b,h] = sum_t smiles[b,t,h] * alphas[b,t]
__global__ __launch_bounds__(256) void pass3(const float* __restrict__ smiles,
                                             const float* __restrict__ alphas,
                                             float* __restrict__ out) {
  int b = blockIdx.y;
  int t0 = blockIdx.x * 128;
  int tid = threadIdx.x;
  int tg = tid >> 7;             // 0/1 -> even/odd t
  int h4 = (tid & 127) * 4;
  const float* sb = smiles + (size_t)b * T_ * H_;
  f32x4 acc = (f32x4){0.f, 0.f, 0.f, 0.f};
  #pragma unroll 4
  for (int i = 0; i < 64; ++i) {
    int t = t0 + 2 * i + tg;
    float al = alphas[b * T_ + t];
    float4 sv = *reinterpret_cast<const float4*>(sb + (size_t)t * H_ + h4);
    acc.x += al * sv.x; acc.y += al * sv.y;
    acc.z += al * sv.z; acc.w += al * sv.w;
  }
  float* op = out + b * H_ + h4;
  atomicAdd(op + 0, acc.x); atomicAdd(op + 1, acc.y);
  atomicAdd(op + 2, acc.z); atomicAdd(op + 3, acc.w);
}

extern "C" void kernel_launch(void* const* d_in, const int* in_sizes, int n_in,
                              void* d_out, int out_size, void* d_ws, size_t ws_size,
                              hipStream_t stream) {
  const float* genes  = (const float*)d_in[0];
  const float* smiles = (const float*)d_in[1];
  const float* w0     = (const float*)d_in[2];
  const float* wg     = (const float*)d_in[3];
  const float* bg     = (const float*)d_in[4];
  const float* dk     = (const float*)d_in[5];
  const float* db     = (const float*)d_in[6];
  const float* v      = (const float*)d_in[7];
  float* out = (float*)d_out;            // [B,H] output then [B,T] alphas
  char* ws = (char*)d_ws;
  float* gp = (float*)ws;                                    // 128 KB
  unsigned short* khi = (unsigned short*)(ws + 131072);      // 256 KB
  unsigned short* klo = (unsigned short*)(ws + 131072 + 262144); // 256 KB
  float* xv = (float*)(ws + 131072 + 524288);                // 512 KB
  float* alphas = out + B_ * H_;

  hipMemsetAsync(gp, 0, B_ * A_ * sizeof(float), stream);
  hipMemsetAsync(out, 0, B_ * H_ * sizeof(float), stream);
  prep_kt<<<512, 256, 0, stream>>>(dk, khi, klo);
  gene_proj_k<<<dim3(B_, 4), 256, 0, stream>>>(genes, w0, wg, bg, db, gp);
  pass1<<<dim3(T_ / 64, B_), 256, 0, stream>>>(smiles, khi, klo, gp, v, xv);
  softmax_k<<<B_, 256, 0, stream>>>(xv, alphas);
  pass3<<<dim3(8, B_), 256, 0, stream>>>(smiles, alphas, out);
}

// Round 2
// 526.604 us; speedup vs baseline: 1.0346x; 1.0346x over previous
//
#include <hip/hip_runtime.h>
#include <stdint.h>

#define B_ 128
#define T_ 1024
#define H_ 512
#define A_ 256
#define G_ 2128

typedef short s16x8 __attribute__((ext_vector_type(8)));
typedef float f32x4 __attribute__((ext_vector_type(4)));

__device__ inline unsigned short f2bf(float f) {
  unsigned u = __float_as_uint(f);
  u += 0x7fff + ((u >> 16) & 1);   // round-to-nearest-even
  return (unsigned short)(u >> 16);
}
__device__ inline unsigned pack2bf(float a, float b) {
  return ((unsigned)f2bf(b) << 16) | f2bf(a);
}
__device__ inline float fast_tanh(float x) {
  x = fminf(15.f, fmaxf(-15.f, x));
  float e = __expf(2.f * x);
  return (e - 1.f) * __builtin_amdgcn_rcpf(e + 1.f);
}

// K^T bf16, tile-major [kb][a][k_in_tile], kb=k/32: 16 tiles of 256x32.
// Coalesced reads of dense_kernel [H][A]; scattered 2B writes (2MB total, cheap).
__global__ void prep_kt(const float* __restrict__ K,
                        unsigned short* __restrict__ khi) {
  int idx = blockIdx.x * 256 + threadIdx.x;   // h*256 + a
  int h = idx >> 8;
  int a = idx & 255;
  khi[(h >> 5) * 8192 + a * 32 + (h & 31)] = f2bf(K[idx]);
}

// gp[b][a] = w0 * sum_g genes[b,g]*Wg[g,a] + b_genes[a] + dense_bias[a]
__global__ __launch_bounds__(256) void gene_proj_k(
    const float* __restrict__ genes, const float* __restrict__ w0p,
    const float* __restrict__ Wg, const float* __restrict__ bg,
    const float* __restrict__ db, float* __restrict__ gp) {
  int b = blockIdx.x;
  int a = threadIdx.x;
  const float* gb = genes + (size_t)b * G_;
  float s = 0.f;
  #pragma unroll 4
  for (int g4 = 0; g4 < G_ / 4; ++g4) {
    float4 gv = *reinterpret_cast<const float4*>(gb + g4 * 4);
    s = fmaf(gv.x, Wg[(g4 * 4 + 0) * A_ + a], s);
    s = fmaf(gv.y, Wg[(g4 * 4 + 1) * A_ + a], s);
    s = fmaf(gv.z, Wg[(g4 * 4 + 2) * A_ + a], s);
    s = fmaf(gv.w, Wg[(g4 * 4 + 3) * A_ + a], s);
  }
  gp[b * A_ + a] = w0p[0] * s + bg[a] + db[a];
}

// Pass 1: block = 64 t x 256 a, 4 waves (wave w: all 64 t, a in [w*64,w*64+64)).
// LDS XOR-swizzle: 16B group g of row r stored at physical group g^(r&3).
__global__ __launch_bounds__(256, 4) void pass1(
    const float* __restrict__ smiles, const unsigned short* __restrict__ khi,
    const float* __restrict__ gp, const float* __restrict__ v,
    float* __restrict__ xv) {
  __shared__ unsigned short sA[64 * 32];    // smiles tile bf16, 4 KB
  __shared__ unsigned short sB[256 * 32];   // K^T tile, 16 KB
  __shared__ float sXV[64 * 4];             // per-wave xv partials

  const int tid = threadIdx.x;
  const int b = blockIdx.y;
  const int t0 = blockIdx.x * 64;
  const int lane = tid & 63;
  const int w = tid >> 6;
  const int n = lane & 15;
  const int q = lane >> 4;

  const float* sb = smiles + ((size_t)b * T_ + t0) * H_;

  f32x4 acc[4][4];
  #pragma unroll
  for (int i = 0; i < 4; ++i)
    #pragma unroll
    for (int j = 0; j < 4; ++j)
      acc[i][j] = (f32x4){0.f, 0.f, 0.f, 0.f};

  const int ar = tid >> 2;          // sA staging: row 0..63
  const int ac = tid & 3;           // sA staging: group 0..3
  const int swA = (ac ^ (ar & 3)) * 8;
  const int swB0 = (0 ^ (tid & 3)) * 8;   // sB staging: row=tid, groups 0..3
  const int swB1 = (1 ^ (tid & 3)) * 8;
  const int swB2 = (2 ^ (tid & 3)) * 8;
  const int swB3 = (3 ^ (tid & 3)) * 8;

  for (int kb = 0; kb < 16; ++kb) {
    const int k0 = kb * 32;
    __syncthreads();
    // stage smiles 64x32 fp32 -> bf16 (thread: 8 floats)
    {
      const float* src = sb + ar * H_ + k0 + ac * 8;
      float4 f0 = *reinterpret_cast<const float4*>(src);
      float4 f1 = *reinterpret_cast<const float4*>(src + 4);
      uint4 p;
      p.x = pack2bf(f0.x, f0.y); p.y = pack2bf(f0.z, f0.w);
      p.z = pack2bf(f1.x, f1.y); p.w = pack2bf(f1.z, f1.w);
      *reinterpret_cast<uint4*>(&sA[ar * 32 + swA]) = p;
    }
    // stage K^T 256x32 (thread: one full row, 64 B contiguous)
    {
      const uint4* src = reinterpret_cast<const uint4*>(khi + kb * 8192 + tid * 32);
      uint4 q0 = src[0], q1 = src[1], q2 = src[2], q3 = src[3];
      unsigned short* row = &sB[tid * 32];
      *reinterpret_cast<uint4*>(row + swB0) = q0;
      *reinterpret_cast<uint4*>(row + swB1) = q1;
      *reinterpret_cast<uint4*>(row + swB2) = q2;
      *reinterpret_cast<uint4*>(row + swB3) = q3;
    }
    __syncthreads();

    s16x8 af[4], bh[4];
    const int sw = (q ^ (n & 3)) * 8;
    #pragma unroll
    for (int i = 0; i < 4; ++i)
      af[i] = *reinterpret_cast<const s16x8*>(&sA[(i * 16 + n) * 32 + sw]);
    #pragma unroll
    for (int j = 0; j < 4; ++j)
      bh[j] = *reinterpret_cast<const s16x8*>(&sB[(w * 64 + j * 16 + n) * 32 + sw]);
    #pragma unroll
    for (int i = 0; i < 4; ++i)
      #pragma unroll
      for (int j = 0; j < 4; ++j)
        acc[i][j] = __builtin_amdgcn_mfma_f32_16x16x32_bf16(af[i], bh[j], acc[i][j], 0, 0, 0);
  }

  // epilogue: sum_a v_a * tanh(gp + proj); D: t = q*4+r (+16i), a = n (+16j+64w)
  float vv[4], gg[4];
  #pragma unroll
  for (int j = 0; j < 4; ++j) {
    int a = w * 64 + j * 16 + n;
    vv[j] = v[a];
    gg[j] = gp[b * A_ + a];
  }
  #pragma unroll
  for (int i = 0; i < 4; ++i) {
    #pragma unroll
    for (int r = 0; r < 4; ++r) {
      float s = 0.f;
      #pragma unroll
      for (int j = 0; j < 4; ++j)
        s += vv[j] * fast_tanh(acc[i][j][r] + gg[j]);
      s += __shfl_xor(s, 1); s += __shfl_xor(s, 2);
      s += __shfl_xor(s, 4); s += __shfl_xor(s, 8);
      if (n == 0) sXV[(i * 16 + q * 4 + r) * 4 + w] = s;
    }
  }
  __syncthreads();
  if (tid < 64) {
    float* p = &sXV[tid * 4];
    xv[(size_t)b * T_ + t0 + tid] = p[0] + p[1] + p[2] + p[3];
  }
}

__global__ __launch_bounds__(256) void softmax_k(const float* __restrict__ xv,
                                                 float* __restrict__ alphas) {
  __shared__ float red[8];
  int b = blockIdx.x, tid = threadIdx.x;
  float4 x = *reinterpret_cast<const float4*>(xv + b * T_ + tid * 4);
  float m = fmaxf(fmaxf(x.x, x.y), fmaxf(x.z, x.w));
  #pragma unroll
  for (int o = 1; o < 64; o <<= 1) m = fmaxf(m, __shfl_xor(m, o));
  if ((tid & 63) == 0) red[tid >> 6] = m;
  __syncthreads();
  m = fmaxf(fmaxf(red[0], red[1]), fmaxf(red[2], red[3]));
  float e0 = __expf(x.x - m), e1 = __expf(x.y - m);
  float e2 = __expf(x.z - m), e3 = __expf(x.w - m);
  float s = e0 + e1 + e2 + e3;
  #pragma unroll
  for (int o = 1; o < 64; o <<= 1) s += __shfl_xor(s, o);
  if ((tid & 63) == 0) red[4 + (tid >> 6)] = s;
  __syncthreads();
  s = red[4] + red[5] + red[6] + red[7];
  float inv = 1.f / s;
  float4 o4;
  o4.x = e0 * inv; o4.y = e1 * inv; o4.z = e2 * inv; o4.w = e3 * inv;
  *reinterpret_cast<float4*>(alphas + b * T_ + tid * 4) = o4;
}

// out[b,h] = sum_t smiles[b,t,h] * alphas[b,t]; t-tile 64 -> 2048 blocks.
__global__ __launch_bounds__(256) void pass3(const float* __restrict__ smiles,
                                             const float* __restrict__ alphas,
                                             float* __restrict__ out) {
  int b = blockIdx.y;
  int t0 = blockIdx.x * 64;
  int tid = threadIdx.x;
  int tg = tid >> 7;             // even/odd t
  int h4 = (tid & 127) * 4;
  const float* sb = smiles + (size_t)b * T_ * H_;
  f32x4 acc = (f32x4){0.f, 0.f, 0.f, 0.f};
  #pragma unroll 8
  for (int i = 0; i < 32; ++i) {
    int t = t0 + 2 * i + tg;
    float al = alphas[b * T_ + t];
    float4 sv = *reinterpret_cast<const float4*>(sb + (size_t)t * H_ + h4);
    acc.x = fmaf(al, sv.x, acc.x); acc.y = fmaf(al, sv.y, acc.y);
    acc.z = fmaf(al, sv.z, acc.z); acc.w = fmaf(al, sv.w, acc.w);
  }
  float* op = out + b * H_ + h4;
  atomicAdd(op + 0, acc.x); atomicAdd(op + 1, acc.y);
  atomicAdd(op + 2, acc.z); atomicAdd(op + 3, acc.w);
}

extern "C" void kernel_launch(void* const* d_in, const int* in_sizes, int n_in,
                              void* d_out, int out_size, void* d_ws, size_t ws_size,
                              hipStream_t stream) {
  const float* genes  = (const float*)d_in[0];
  const float* smiles = (const float*)d_in[1];
  const float* w0     = (const float*)d_in[2];
  const float* wg     = (const float*)d_in[3];
  const float* bg     = (const float*)d_in[4];
  const float* dk     = (const float*)d_in[5];
  const float* db     = (const float*)d_in[6];
  const float* v      = (const float*)d_in[7];
  float* out = (float*)d_out;            // [B,H] output then [B,T] alphas
  char* ws = (char*)d_ws;
  float* gp = (float*)ws;                                    // 128 KB
  unsigned short* khi = (unsigned short*)(ws + 131072);      // 256 KB
  float* xv = (float*)(ws + 131072 + 262144);                // 512 KB
  float* alphas = out + B_ * H_;

  hipMemsetAsync(out, 0, B_ * H_ * sizeof(float), stream);
  prep_kt<<<512, 256, 0, stream>>>(dk, khi);
  gene_proj_k<<<B_, 256, 0, stream>>>(genes, w0, wg, bg, db, gp);
  pass1<<<dim3(T_ / 64, B_), 256, 0, stream>>>(smiles, khi, gp, v, xv);
  softmax_k<<<B_, 256, 0, stream>>>(xv, alphas);
  pass3<<<dim3(16, B_), 256, 0, stream>>>(smiles, alphas, out);
}